// Round 5
// baseline (81.133 us; speedup 1.0000x reference)
//
#include <hip/hip_runtime.h>
#include <math.h>

#define OBS 2264
#define ACT 32
#define HID 4096
#define VOX 216
#define PRE (OBS - VOX)    // 2048
#define N4_OBS (OBS / 4)   // 566
#define N4_HID (HID / 4)   // 1024
#define NB 256             // blocks (1 per CU nominally; co-residency guaranteed)
#define NT 1024            // threads per block (16 waves)
#define RPB 16             // rows per block per GEMV layer (4096/256)
#define RPG 4              // rows per 256-thread group

// ---------------------------------------------------------------------------
// Grid barrier: monotonic counter, each arrival waits for the next multiple
// of NB above its own ticket. Works across multiple sequential barriers and
// across replays WITHOUT reset (counter only grows; zeroed each launch by
// hipMemsetAsync). AGENT-scope atomics = cross-XCD coherent. Bounded spin:
// a pathological stall produces a wrong answer (bench fails), never a hang.
// ---------------------------------------------------------------------------
__device__ __forceinline__ void grid_barrier(unsigned* cnt, int tid) {
    __syncthreads();
    if (tid == 0) {
        __threadfence();   // release: make our global stores visible device-wide
        const unsigned old = __hip_atomic_fetch_add(cnt, 1u, __ATOMIC_ACQ_REL,
                                                    __HIP_MEMORY_SCOPE_AGENT);
        const unsigned target = (old / NB + 1u) * NB;
        unsigned guard = 0;
        while (__hip_atomic_load(cnt, __ATOMIC_ACQUIRE,
                                 __HIP_MEMORY_SCOPE_AGENT) < target) {
            __builtin_amdgcn_s_sleep(2);
            if (++guard > (1u << 24)) break;   // fail loud, not hang
        }
        __threadfence();   // acquire: discard stale cached lines
    }
    __syncthreads();
}

// ---------------------------------------------------------------------------
// Persistent kernel: conv chain + norm (per-block, LDS) -> gemv0 -> [gbar]
// -> gemv1 -> [gbar] -> gemv_out. 256 blocks x 1024 threads.
// ---------------------------------------------------------------------------
__global__ __launch_bounds__(NT) void persistent_kernel(
    const float* __restrict__ x,
    const float* __restrict__ cw0, const float* __restrict__ cb0,
    const float* __restrict__ cw1, const float* __restrict__ cb1,
    const float* __restrict__ cw2, const float* __restrict__ cb2,
    const float* __restrict__ cw3, const float* __restrict__ cb3,
    const float* __restrict__ cw4, const float* __restrict__ cb4,
    const float* __restrict__ cw5, const float* __restrict__ cb5,
    const float* __restrict__ in_shift, const float* __restrict__ in_scale,
    const float* __restrict__ W0, const float* __restrict__ b0,
    const float* __restrict__ W1, const float* __restrict__ b1,
    const float* __restrict__ W2, const float* __restrict__ b2,
    const float* __restrict__ oscale, const float* __restrict__ oshift,
    unsigned* __restrict__ bar,
    float* __restrict__ h0, float* __restrict__ h1,
    float* __restrict__ y)
{
    __shared__ float skw[6][27];
    __shared__ float skb[6];
    __shared__ float vbA[VOX], vbB[VOX];
    __shared__ __align__(16) float su[OBS];
    __shared__ float part[4][RPG][4];   // [group][row][wave]
    __shared__ float part16[16];

    const int tid = threadIdx.x;

    // ---- stage conv weights/biases + voxel tail (scratch-free, static idx) ----
    if (tid < 162) {
        const float* srcw = tid < 27  ? cw0
                          : tid < 54  ? cw1
                          : tid < 81  ? cw2
                          : tid < 108 ? cw3
                          : tid < 135 ? cw4 : cw5;
        const int base = tid < 27  ? 0
                       : tid < 54  ? 27
                       : tid < 81  ? 54
                       : tid < 108 ? 81
                       : tid < 135 ? 108 : 135;
        reinterpret_cast<float*>(skw)[tid] = srcw[tid - base];
    } else if (tid >= 192 && tid < 198) {
        const float* srcb = tid == 192 ? cb0
                          : tid == 193 ? cb1
                          : tid == 194 ? cb2
                          : tid == 195 ? cb3
                          : tid == 196 ? cb4 : cb5;
        skb[tid - 192] = srcb[0];
    }
    if (tid < VOX) vbA[tid] = x[PRE + tid];
    __syncthreads();

    const int d = tid / 36;
    const int h = (tid / 6) % 6;
    const int w = tid % 6;

#define CONV_LAYER(L, SRC, DST)                                              \
    if (tid < VOX) {                                                         \
        float acc = skb[L];                                                  \
        _Pragma("unroll") for (int kd = 0; kd < 3; ++kd) {                   \
            const int dd = d + kd - 1;                                       \
            if (dd >= 0 && dd <= 5) {                                        \
                _Pragma("unroll") for (int kh = 0; kh < 3; ++kh) {           \
                    const int hh = h + kh - 1;                               \
                    if (hh >= 0 && hh <= 5) {                                \
                        _Pragma("unroll") for (int kw2 = 0; kw2 < 3; ++kw2) {\
                            const int ww = w + kw2 - 1;                      \
                            if (ww >= 0 && ww <= 5)                          \
                                acc += skw[L][kd * 9 + kh * 3 + kw2]         \
                                     * SRC[dd * 36 + hh * 6 + ww];           \
                        }                                                    \
                    }                                                        \
                }                                                            \
            }                                                                \
        }                                                                    \
        DST[tid] = fmaxf(acc, 0.f);                                          \
    }                                                                        \
    __syncthreads();

    CONV_LAYER(0, vbA, vbB)
    CONV_LAYER(1, vbB, vbA)
    CONV_LAYER(2, vbA, vbB)
    CONV_LAYER(3, vbB, vbA)
    CONV_LAYER(4, vbA, vbB)
    CONV_LAYER(5, vbB, vbA)
#undef CONV_LAYER

    // ---- input normalization into LDS ----
    for (int i = tid; i < OBS; i += NT) {
        const float val = (i < PRE) ? x[i] : vbA[i - PRE];
        su[i] = (val - in_shift[i]) / (in_scale[i] + 1e-8f);
    }
    __syncthreads();

    const int g = tid >> 8;       // 0..3
    const int t = tid & 255;

    // ---- gemv0: h0 = tanh(W0 . u + b0), 16 rows/block ----
    {
        const int r0 = blockIdx.x * RPB + g * RPG;
        const float4* __restrict__ su4 = reinterpret_cast<const float4*>(su);
        const float4* __restrict__ W4  = reinterpret_cast<const float4*>(W0);
        float accs[RPG] = {0.f, 0.f, 0.f, 0.f};
        for (int j = t; j < N4_OBS; j += 256) {
            const float4 uv = su4[j];
            #pragma unroll
            for (int r = 0; r < RPG; ++r) {
                const float4 wv = W4[(size_t)(r0 + r) * N4_OBS + j];
                accs[r] += wv.x * uv.x + wv.y * uv.y + wv.z * uv.z + wv.w * uv.w;
            }
        }
        #pragma unroll
        for (int r = 0; r < RPG; ++r) {
            float a = accs[r];
            #pragma unroll
            for (int off = 32; off > 0; off >>= 1) a += __shfl_down(a, off, 64);
            if ((t & 63) == 0) part[g][r][t >> 6] = a;
        }
        __syncthreads();
        if (t < RPG) {
            const float s = part[g][t][0] + part[g][t][1] + part[g][t][2]
                          + part[g][t][3] + b0[r0 + t];
            h0[r0 + t] = tanhf(s);
        }
    }

    grid_barrier(bar, tid);

    // ---- gemv1: h1 = tanh(W1 . h0 + b1), 16 rows/block ----
    {
        const int r0 = blockIdx.x * RPB + g * RPG;
        const float4* __restrict__ u4 = reinterpret_cast<const float4*>(h0);
        const float4* __restrict__ W4 = reinterpret_cast<const float4*>(W1);
        float accs[RPG] = {0.f, 0.f, 0.f, 0.f};
        for (int j = t; j < N4_HID; j += 256) {
            const float4 uv = u4[j];
            #pragma unroll
            for (int r = 0; r < RPG; ++r) {
                const float4 wv = W4[(size_t)(r0 + r) * N4_HID + j];
                accs[r] += wv.x * uv.x + wv.y * uv.y + wv.z * uv.z + wv.w * uv.w;
            }
        }
        #pragma unroll
        for (int r = 0; r < RPG; ++r) {
            float a = accs[r];
            #pragma unroll
            for (int off = 32; off > 0; off >>= 1) a += __shfl_down(a, off, 64);
            if ((t & 63) == 0) part[g][r][t >> 6] = a;
        }
        __syncthreads();
        if (t < RPG) {
            const float s = part[g][t][0] + part[g][t][1] + part[g][t][2]
                          + part[g][t][3] + b1[r0 + t];
            h1[r0 + t] = tanhf(s);
        }
    }

    grid_barrier(bar, tid);

    // ---- gemv_out: y = (W2 . h1 + b2) * oscale + oshift, blocks 0..31 ----
    if (blockIdx.x < ACT) {
        const int row = blockIdx.x;
        const float4* __restrict__ Wr =
            reinterpret_cast<const float4*>(W2 + (size_t)row * HID);
        const float4* __restrict__ u4 = reinterpret_cast<const float4*>(h1);
        const float4 wv = Wr[tid];
        const float4 uv = u4[tid];
        float a = wv.x * uv.x + wv.y * uv.y + wv.z * uv.z + wv.w * uv.w;
        #pragma unroll
        for (int off = 32; off > 0; off >>= 1) a += __shfl_down(a, off, 64);
        if ((tid & 63) == 0) part16[tid >> 6] = a;
        __syncthreads();
        if (tid == 0) {
            float s = b2[row];
            #pragma unroll
            for (int i = 0; i < 16; ++i) s += part16[i];
            y[row] = s * oscale[row] + oshift[row];
        }
    }
}

extern "C" void kernel_launch(void* const* d_in, const int* in_sizes, int n_in,
                              void* d_out, int out_size, void* d_ws, size_t ws_size,
                              hipStream_t stream) {
    const float* x = (const float*)d_in[0];

    const float* cw[6];
    const float* cb[6];
    if (in_sizes[2] == 1) {           // interleaved: x, cw0, cb0, cw1, cb1, ...
        for (int i = 0; i < 6; ++i) {
            cw[i] = (const float*)d_in[1 + 2 * i];
            cb[i] = (const float*)d_in[2 + 2 * i];
        }
    } else {                          // grouped: x, cw0..cw5, cb0..cb5
        for (int i = 0; i < 6; ++i) {
            cw[i] = (const float*)d_in[1 + i];
            cb[i] = (const float*)d_in[7 + i];
        }
    }
    const float* W0       = (const float*)d_in[13];
    const float* b0       = (const float*)d_in[14];
    const float* W1       = (const float*)d_in[15];
    const float* b1       = (const float*)d_in[16];
    const float* W2       = (const float*)d_in[17];
    const float* b2       = (const float*)d_in[18];
    const float* in_shift = (const float*)d_in[19];
    const float* in_scale = (const float*)d_in[20];
    const float* oshift   = (const float*)d_in[21];
    const float* oscale   = (const float*)d_in[22];

    // ws layout: [0,64) floats = barrier counters (zeroed every launch);
    //            [64, 64+4096) = h0; [64+4096, 64+8192) = h1.
    unsigned* bar = (unsigned*)d_ws;
    float*    wsf = (float*)d_ws;
    float*    h0  = wsf + 64;
    float*    h1  = wsf + 64 + HID;
    float*    y   = (float*)d_out;

    hipMemsetAsync(d_ws, 0, 256, stream);   // capture-safe memset node

    persistent_kernel<<<NB, NT, 0, stream>>>(
        x, cw[0], cb[0], cw[1], cb[1], cw[2], cb[2],
        cw[3], cb[3], cw[4], cb[4], cw[5], cb[5],
        in_shift, in_scale, W0, b0, W1, b1, W2, b2,
        oscale, oshift, bar, h0, h1, y);
}

// Round 7
// 40.883 us; speedup vs baseline: 1.9845x; 1.9845x over previous
//
#include <hip/hip_runtime.h>
#include <math.h>

#define OBS 2264
#define ACT 32
#define HID 4096
#define VOX 216
#define PRE (OBS - VOX)    // 2048
#define N4_OBS (OBS / 4)   // 566
#define N4_HID (HID / 4)   // 1024
#define NB 256             // one block per CU
#define NT 1024            // 16 waves
#define RPB 16             // rows per block (4096/256)
#define RPG 4              // rows per 256-thread group

// ---------------------------------------------------------------------------
// K1: conv chain + norm (redundant per block, but exactly 1 block/CU so each
// CU pays the ~2.6 µs conv VALU cost once, hidden under W0 streaming)
// + GEMV W0 (16 rows/block) + tanh -> h0.
// ---------------------------------------------------------------------------
__global__ __launch_bounds__(NT) void fused0_kernel(
    const float* __restrict__ x,
    const float* __restrict__ cw0, const float* __restrict__ cb0,
    const float* __restrict__ cw1, const float* __restrict__ cb1,
    const float* __restrict__ cw2, const float* __restrict__ cb2,
    const float* __restrict__ cw3, const float* __restrict__ cb3,
    const float* __restrict__ cw4, const float* __restrict__ cb4,
    const float* __restrict__ cw5, const float* __restrict__ cb5,
    const float* __restrict__ in_shift, const float* __restrict__ in_scale,
    const float* __restrict__ W0, const float* __restrict__ b0,
    float* __restrict__ h0)
{
    __shared__ float skw[6][27];
    __shared__ float skb[6];
    __shared__ float vbA[VOX], vbB[VOX];
    __shared__ __align__(16) float su[OBS];
    __shared__ float part[4][RPG][4];   // [group][row][wave-in-group]

    const int tid = threadIdx.x;

    // ---- stage conv weights/biases + voxel tail (static idx, no scratch) ----
    if (tid < 162) {
        const float* srcw = tid < 27  ? cw0
                          : tid < 54  ? cw1
                          : tid < 81  ? cw2
                          : tid < 108 ? cw3
                          : tid < 135 ? cw4 : cw5;
        const int base = tid < 27  ? 0
                       : tid < 54  ? 27
                       : tid < 81  ? 54
                       : tid < 108 ? 81
                       : tid < 135 ? 108 : 135;
        reinterpret_cast<float*>(skw)[tid] = srcw[tid - base];
    } else if (tid >= 192 && tid < 198) {
        const float* srcb = tid == 192 ? cb0
                          : tid == 193 ? cb1
                          : tid == 194 ? cb2
                          : tid == 195 ? cb3
                          : tid == 196 ? cb4 : cb5;
        skb[tid - 192] = srcb[0];
    }
    if (tid < VOX) vbA[tid] = x[PRE + tid];
    __syncthreads();

    const int d = tid / 36;
    const int h = (tid / 6) % 6;
    const int w = tid % 6;

#define CONV_LAYER(L, SRC, DST)                                              \
    if (tid < VOX) {                                                         \
        float acc = skb[L];                                                  \
        _Pragma("unroll") for (int kd = 0; kd < 3; ++kd) {                   \
            const int dd = d + kd - 1;                                       \
            if (dd >= 0 && dd <= 5) {                                        \
                _Pragma("unroll") for (int kh = 0; kh < 3; ++kh) {           \
                    const int hh = h + kh - 1;                               \
                    if (hh >= 0 && hh <= 5) {                                \
                        _Pragma("unroll") for (int kw2 = 0; kw2 < 3; ++kw2) {\
                            const int ww = w + kw2 - 1;                      \
                            if (ww >= 0 && ww <= 5)                          \
                                acc += skw[L][kd * 9 + kh * 3 + kw2]         \
                                     * SRC[dd * 36 + hh * 6 + ww];           \
                        }                                                    \
                    }                                                        \
                }                                                            \
            }                                                                \
        }                                                                    \
        DST[tid] = fmaxf(acc, 0.f);                                          \
    }                                                                        \
    __syncthreads();

    CONV_LAYER(0, vbA, vbB)
    CONV_LAYER(1, vbB, vbA)
    CONV_LAYER(2, vbA, vbB)
    CONV_LAYER(3, vbB, vbA)
    CONV_LAYER(4, vbA, vbB)
    CONV_LAYER(5, vbB, vbA)
#undef CONV_LAYER
    // result in vbA

    // ---- input normalization into LDS (3 iters at 1024 threads) ----
    for (int i = tid; i < OBS; i += NT) {
        const float val = (i < PRE) ? x[i] : vbA[i - PRE];
        su[i] = (val - in_shift[i]) / (in_scale[i] + 1e-8f);
    }
    __syncthreads();

    // ---- GEMV W0: 16 rows/block, 4 rows per 256-thread group ----
    const int g = tid >> 8;     // 0..3
    const int t = tid & 255;
    const int r0 = blockIdx.x * RPB + g * RPG;
    const float4* __restrict__ su4 = reinterpret_cast<const float4*>(su);
    const float4* __restrict__ W4  = reinterpret_cast<const float4*>(W0);

    float accs[RPG] = {0.f, 0.f, 0.f, 0.f};
    for (int j = t; j < N4_OBS; j += 256) {
        const float4 uv = su4[j];
        #pragma unroll
        for (int r = 0; r < RPG; ++r) {
            const float4 wv = W4[(size_t)(r0 + r) * N4_OBS + j];
            accs[r] += wv.x * uv.x + wv.y * uv.y + wv.z * uv.z + wv.w * uv.w;
        }
    }
    #pragma unroll
    for (int r = 0; r < RPG; ++r) {
        float a = accs[r];
        #pragma unroll
        for (int off = 32; off > 0; off >>= 1) a += __shfl_down(a, off, 64);
        if ((t & 63) == 0) part[g][r][t >> 6] = a;
    }
    __syncthreads();
    if (t < RPG) {
        const float s = part[g][t][0] + part[g][t][1] + part[g][t][2]
                      + part[g][t][3] + b0[r0 + t];
        h0[r0 + t] = tanhf(s);
    }
}

// ---------------------------------------------------------------------------
// K2: GEMV W1 [4096,4096] + tanh. 256 blocks x 1024 threads, 16 rows/block.
// h0 staged in LDS (one float4 per thread).
// ---------------------------------------------------------------------------
__global__ __launch_bounds__(NT) void gemv1_kernel(
    const float* __restrict__ W, const float* __restrict__ b,
    const float* __restrict__ u, float* __restrict__ out)
{
    __shared__ __align__(16) float sh[HID];
    __shared__ float part[4][RPG][4];

    const int tid = threadIdx.x;

    // stage h0 -> LDS
    reinterpret_cast<float4*>(sh)[tid] =
        reinterpret_cast<const float4*>(u)[tid];
    __syncthreads();

    const int g = tid >> 8;
    const int t = tid & 255;
    const int r0 = blockIdx.x * RPB + g * RPG;
    const float4* __restrict__ u4 = reinterpret_cast<const float4*>(sh);
    const float4* __restrict__ W4 = reinterpret_cast<const float4*>(W);

    float accs[RPG] = {0.f, 0.f, 0.f, 0.f};
    for (int j = t; j < N4_HID; j += 256) {
        const float4 uv = u4[j];
        #pragma unroll
        for (int r = 0; r < RPG; ++r) {
            const float4 wv = W4[(size_t)(r0 + r) * N4_HID + j];
            accs[r] += wv.x * uv.x + wv.y * uv.y + wv.z * uv.z + wv.w * uv.w;
        }
    }
    #pragma unroll
    for (int r = 0; r < RPG; ++r) {
        float a = accs[r];
        #pragma unroll
        for (int off = 32; off > 0; off >>= 1) a += __shfl_down(a, off, 64);
        if ((t & 63) == 0) part[g][r][t >> 6] = a;
    }
    __syncthreads();
    if (t < RPG) {
        const float s = part[g][t][0] + part[g][t][1] + part[g][t][2]
                      + part[g][t][3] + b[r0 + t];
        out[r0 + t] = tanhf(s);
    }
}

// ---------------------------------------------------------------------------
// K3: final GEMV [32,4096] + output affine. 32 blocks x 1024 threads.
// ---------------------------------------------------------------------------
__global__ __launch_bounds__(NT) void gemv_out_kernel(
    const float* __restrict__ W, const float* __restrict__ b,
    const float* __restrict__ u,
    const float* __restrict__ oscale, const float* __restrict__ oshift,
    float* __restrict__ out)
{
    const int row = blockIdx.x;
    const int tid = threadIdx.x;
    const float4* __restrict__ Wr =
        reinterpret_cast<const float4*>(W + (size_t)row * HID);
    const float4* __restrict__ u4 = reinterpret_cast<const float4*>(u);

    const float4 wv = Wr[tid];
    const float4 uv = u4[tid];
    float a = wv.x * uv.x + wv.y * uv.y + wv.z * uv.z + wv.w * uv.w;

    #pragma unroll
    for (int off = 32; off > 0; off >>= 1) a += __shfl_down(a, off, 64);

    __shared__ float part16[16];
    if ((tid & 63) == 0) part16[tid >> 6] = a;
    __syncthreads();
    if (tid == 0) {
        float s = b[row];
        #pragma unroll
        for (int i = 0; i < 16; ++i) s += part16[i];
        out[row] = s * oscale[row] + oshift[row];
    }
}

extern "C" void kernel_launch(void* const* d_in, const int* in_sizes, int n_in,
                              void* d_out, int out_size, void* d_ws, size_t ws_size,
                              hipStream_t stream) {
    const float* x = (const float*)d_in[0];

    const float* cw[6];
    const float* cb[6];
    if (in_sizes[2] == 1) {           // interleaved: x, cw0, cb0, cw1, cb1, ...
        for (int i = 0; i < 6; ++i) {
            cw[i] = (const float*)d_in[1 + 2 * i];
            cb[i] = (const float*)d_in[2 + 2 * i];
        }
    } else {                          // grouped: x, cw0..cw5, cb0..cb5
        for (int i = 0; i < 6; ++i) {
            cw[i] = (const float*)d_in[1 + i];
            cb[i] = (const float*)d_in[7 + i];
        }
    }
    const float* W0       = (const float*)d_in[13];
    const float* b0       = (const float*)d_in[14];
    const float* W1       = (const float*)d_in[15];
    const float* b1       = (const float*)d_in[16];
    const float* W2       = (const float*)d_in[17];
    const float* b2       = (const float*)d_in[18];
    const float* in_shift = (const float*)d_in[19];
    const float* in_scale = (const float*)d_in[20];
    const float* oshift   = (const float*)d_in[21];
    const float* oscale   = (const float*)d_in[22];

    float* ws = (float*)d_ws;
    float* h0 = ws;            // [0, 4096)
    float* h1 = ws + HID;      // [4096, 8192)
    float* y  = (float*)d_out;

    fused0_kernel<<<NB, NT, 0, stream>>>(
        x, cw[0], cb[0], cw[1], cb[1], cw[2], cb[2],
        cw[3], cb[3], cw[4], cb[4], cw[5], cb[5],
        in_shift, in_scale, W0, b0, h0);

    gemv1_kernel<<<NB, NT, 0, stream>>>(W1, b1, h0, h1);
    gemv_out_kernel<<<ACT, NT, 0, stream>>>(W2, b2, h1, oscale, oshift, y);
}